// Round 5
// baseline (550.127 us; speedup 1.0000x reference)
//
#include <hip/hip_runtime.h>
#include <stdint.h>

// Problem constants
// B=2, T=24, N=512, D=128, P=16, HD=16; SCALE=0.25
// temporal arrays layout [B,N,2,24,16]; spatial [B,T,H,N,16]

static const size_t OFF_WP   = 0;                      // packed weights [128][640]
static const size_t TSZ      = 786432;                 // 2*512*2*24*16
static const size_t GSZ      = 1572864;                // 2*24*4*512*16
static const size_t OFF_T0   = 81920;                  // 7 temporal arrays (tq,tk,tv,rtv,tubq,tubk,tubv)
static const size_t OFF_GEOQ = OFF_T0 + 7*TSZ;         // geo q,k,v each GSZ
static const size_t OFF_GEOK = OFF_GEOQ + GSZ;
static const size_t OFF_GEOV = OFF_GEOK + GSZ;
static const size_t OFF_SEM  = OFF_GEOQ + 3*GSZ;       // sem q,k,v each TSZ
static const size_t OFF_RND  = OFF_SEM + 3*TSZ;        // rnd q,k,v each TSZ
static const size_t OFF_PQ   = OFF_RND + 3*TSZ;        // [24576][64]
static const size_t OFF_PK   = OFF_PQ + GSZ;           // [768][64]
static const size_t OFF_PV   = OFF_PK + 49152;
static const size_t OFF_CAT  = OFF_PV + 49152;         // [24576][224]
static const size_t OFF_MB   = OFF_CAT + 24576ull*224; // 3*512*16 u32 mask words

struct PackPtrs {
    const float* w[16];
    const void* msk[3];
};

// ---------------------------------------------------------------------------
// K0: pack weights into [128][640] (zero-pad cols 608..639) + bit-pack masks.
// Mask buffers (jnp bool) may arrive as uint8 (1B/elem), int32 (0/1), or
// float32 (0.0/1.0). For BOTH 4-byte encodings, "word != 0" decodes truth, so
// we only distinguish 4-byte vs 1-byte: scan 64 words — float32 signature
// (every word in {0, 0x3F800000}) OR int32 signature (bytes 1..3 always 0)
// => word-decode; else byte-decode. P(misclassify | random 0.5 bools) ~ 8^-64.
// ---------------------------------------------------------------------------
__global__ __launch_bounds__(256) void pack_kernel(PackPtrs pp, float* __restrict__ ws) {
    int tid = blockIdx.x * 256 + threadIdx.x;
    if (tid < 128 * 640) {
        int k = tid / 640, c = tid % 640;
        float v = 0.f;
        if (c < 608) {
            if (c < 224) {              // 7 temporal mats, each D x 32
                int which = c >> 5, col = c & 31;
                v = pp.w[which][k * 32 + col];
            } else if (c < 416) {       // geo q,k,v, each D x 64
                int cc = c - 224; int which = 7 + (cc >> 6), col = cc & 63;
                v = pp.w[which][k * 64 + col];
            } else {                    // sem q,k,v + rnd q,k,v, each D x 32
                int cc = c - 416; int which = 10 + (cc >> 5), col = cc & 31;
                v = pp.w[which][k * 32 + col];
            }
        }
        ws[OFF_WP + tid] = v;
    } else {
        int w = tid - 128 * 640;
        if (w < 3 * 8192) {
            int mi = w / 8192, rem = w % 8192;
            int base = (rem >> 4) * 512 + (rem & 15) * 32;   // element index of bit 0
            const uint32_t* w32 = (const uint32_t*)pp.msk[mi];
            uint32_t hibytes = 0;      // nonzero => not int32 0/1
            int isfloat = 1;           // stays 1 => every word is 0.0f or 1.0f
            #pragma unroll
            for (int i = 0; i < 64; i++) {
                uint32_t wv = w32[i];
                hibytes |= wv & 0xFFFFFF00u;
                if (wv != 0u && wv != 0x3F800000u) isfloat = 0;
            }
            uint32_t bits = 0;
            if (isfloat || hibytes == 0) {   // 4-byte elements: word != 0 is truth
                const uint32_t* s = w32 + base;
                #pragma unroll
                for (int j = 0; j < 32; j++) bits |= (s[j] != 0u ? 1u : 0u) << j;
            } else {                          // 1-byte elements
                const uint8_t* s = (const uint8_t*)pp.msk[mi] + base;
                #pragma unroll
                for (int j = 0; j < 32; j++) bits |= (s[j] ? 1u : 0u) << j;
            }
            ((uint32_t*)(ws + OFF_MB))[w] = bits;
        }
    }
}

// ---------------------------------------------------------------------------
// K1: projection GEMM x[24576x128] @ Wp[128x608] with scatter epilogue.
// Block: 64 rows, half the col-tiles (grid.y=2, 5 tiles of 64 cols each).
// A staged transposed in LDS (full K=128); W streamed from L1/L2.
// ---------------------------------------------------------------------------
__global__ __launch_bounds__(256, 4) void proj_gemm(const float* __restrict__ x,
                                                    float* __restrict__ ws) {
    __shared__ float a_t[128][68];
    int rb = blockIdx.x * 64;
    int t = threadIdx.x;
    for (int f = t; f < 64 * 32; f += 256) {   // 2048 float4 loads
        int r = f >> 5, kc = f & 31;
        float4 v = *(const float4*)(x + (size_t)(rb + r) * 128 + kc * 4);
        a_t[kc * 4 + 0][r] = v.x; a_t[kc * 4 + 1][r] = v.y;
        a_t[kc * 4 + 2][r] = v.z; a_t[kc * 4 + 3][r] = v.w;
    }
    __syncthreads();
    int tr = t & 15, tc = t >> 4;
    int r0 = tr * 4, c0 = tc * 4;
    int rn[4], rt_[4], rbq[4];
    #pragma unroll
    for (int i = 0; i < 4; i++) {
        int row = rb + r0 + i;
        rn[i] = row & 511;
        int bt = row >> 9;
        rt_[i] = bt % 24; rbq[i] = bt / 24;
    }
    const float* Wp = ws + OFF_WP;
    for (int ct = blockIdx.y * 5; ct < (int)blockIdx.y * 5 + 5; ct++) {
        float acc[4][4] = {{0.f}};
        int cg = ct * 64 + c0;
        const float* wcol = Wp + cg;
        #pragma unroll 8
        for (int k = 0; k < 128; k++) {
            float4 a4 = *(const float4*)&a_t[k][r0];
            float4 b4 = *(const float4*)(wcol + (size_t)k * 640);
            float av[4] = {a4.x, a4.y, a4.z, a4.w};
            float bv[4] = {b4.x, b4.y, b4.z, b4.w};
            #pragma unroll
            for (int i = 0; i < 4; i++)
                #pragma unroll
                for (int j = 0; j < 4; j++) acc[i][j] += av[i] * bv[j];
        }
        if (cg < 608) {
            int d0 = cg & 15;
            #pragma unroll
            for (int i = 0; i < 4; i++) {
                size_t idx;
                if (cg < 224) {
                    int which = cg >> 5, h = (cg >> 4) & 1;
                    idx = OFF_T0 + (size_t)which * TSZ +
                          ((((size_t)rbq[i] * 512 + rn[i]) * 2 + h) * 24 + rt_[i]) * 16 + d0;
                } else if (cg < 416) {
                    int cc = cg - 224, g = cc >> 6, h = (cc >> 4) & 3;
                    idx = OFF_GEOQ + (size_t)g * GSZ +
                          (((size_t)(rbq[i] * 24 + rt_[i]) * 4 + h) * 512 + rn[i]) * 16 + d0;
                } else {
                    int cc = cg - 416; int isr = cc >= 96 ? 1 : 0; cc -= isr * 96;
                    int g = cc >> 5, h = (cc >> 4) & 1;
                    idx = (isr ? OFF_RND : OFF_SEM) + (size_t)g * TSZ +
                          (((size_t)(rbq[i] * 24 + rt_[i]) * 2 + h) * 512 + rn[i]) * 16 + d0;
                }
                *(float4*)(ws + idx) = make_float4(acc[i][0], acc[i][1], acc[i][2], acc[i][3]);
            }
        }
    }
}

// ---------------------------------------------------------------------------
// Generic tiled GEMM: C[M][N] = A[M][K] @ W[K][N] (+bias). BM=BN=64, KT=32.
// M%64==0, N%64==0, K%32==0 for all uses.
// ---------------------------------------------------------------------------
__global__ __launch_bounds__(256, 4) void gemm_tile(const float* __restrict__ A,
                                                    const float* __restrict__ W,
                                                    const float* __restrict__ bias,
                                                    float* __restrict__ C,
                                                    int K, int N) {
    __shared__ float a_t[32][68];
    __shared__ float bs[32][64];
    int rb = blockIdx.x * 64, cb = blockIdx.y * 64;
    int t = threadIdx.x, tr = t & 15, tc = t >> 4;
    float acc[4][4] = {{0.f}};
    for (int k0 = 0; k0 < K; k0 += 32) {
        __syncthreads();
        for (int f = t; f < 512; f += 256) {
            int r = f >> 3, kc = f & 7;
            float4 v = *(const float4*)(A + (size_t)(rb + r) * K + k0 + kc * 4);
            a_t[kc * 4 + 0][r] = v.x; a_t[kc * 4 + 1][r] = v.y;
            a_t[kc * 4 + 2][r] = v.z; a_t[kc * 4 + 3][r] = v.w;
        }
        for (int f = t; f < 512; f += 256) {
            int kk = f >> 4, cc = f & 15;
            *(float4*)&bs[kk][cc * 4] = *(const float4*)(W + (size_t)(k0 + kk) * N + cb + cc * 4);
        }
        __syncthreads();
        #pragma unroll
        for (int kk = 0; kk < 32; kk++) {
            float4 a4 = *(const float4*)&a_t[kk][tr * 4];
            float4 b4 = *(const float4*)&bs[kk][tc * 4];
            float av[4] = {a4.x, a4.y, a4.z, a4.w};
            float bv[4] = {b4.x, b4.y, b4.z, b4.w};
            #pragma unroll
            for (int i = 0; i < 4; i++)
                #pragma unroll
                for (int j = 0; j < 4; j++) acc[i][j] += av[i] * bv[j];
        }
    }
    #pragma unroll
    for (int i = 0; i < 4; i++) {
        int row = rb + tr * 4 + i, col = cb + tc * 4;
        float4 o = make_float4(acc[i][0], acc[i][1], acc[i][2], acc[i][3]);
        if (bias) {
            o.x += bias[col]; o.y += bias[col + 1];
            o.z += bias[col + 2]; o.w += bias[col + 3];
        }
        *(float4*)(C + (size_t)row * N + col) = o;
    }
}

// ---------------------------------------------------------------------------
// K3: pattern attention; k_add accumulated into geo_K.
// One block per (b,t); pk/pv [16][64] staged in LDS.
// ---------------------------------------------------------------------------
__global__ __launch_bounds__(256, 4) void pattern_attn(float* __restrict__ ws) {
    __shared__ float pk[16][64];
    __shared__ float pv[16][64];
    int bt = blockIdx.x, t = threadIdx.x;
    {
        int p = t >> 4, cc = t & 15;
        *(float4*)&pk[p][cc * 4] = *(const float4*)(ws + OFF_PK + (size_t)bt * 1024 + p * 64 + cc * 4);
        *(float4*)&pv[p][cc * 4] = *(const float4*)(ws + OFF_PV + (size_t)bt * 1024 + p * 64 + cc * 4);
    }
    __syncthreads();
    for (int rr = 0; rr < 2; rr++) {
        int n = t + rr * 256;
        const float* pqr = ws + OFF_PQ + ((size_t)bt * 512 + n) * 64;
        float s[16];
        #pragma unroll
        for (int p = 0; p < 16; p++) s[p] = 0.f;
        #pragma unroll
        for (int j = 0; j < 16; j++) {
            float4 q4 = *(const float4*)(pqr + j * 4);
            #pragma unroll
            for (int p = 0; p < 16; p++) {
                float4 k4 = *(const float4*)&pk[p][j * 4];
                s[p] += q4.x * k4.x + q4.y * k4.y + q4.z * k4.z + q4.w * k4.w;
            }
        }
        float mx = -3e38f;
        #pragma unroll
        for (int p = 0; p < 16; p++) { s[p] *= 0.25f; mx = fmaxf(mx, s[p]); }
        float l = 0.f;
        #pragma unroll
        for (int p = 0; p < 16; p++) { s[p] = __expf(s[p] - mx); l += s[p]; }
        float inv = 1.f / l;
        #pragma unroll
        for (int j = 0; j < 16; j++) {
            float ax = 0.f, ay = 0.f, az = 0.f, aw = 0.f;
            #pragma unroll
            for (int p = 0; p < 16; p++) {
                float4 v4 = *(const float4*)&pv[p][j * 4];
                ax += s[p] * v4.x; ay += s[p] * v4.y; az += s[p] * v4.z; aw += s[p] * v4.w;
            }
            int h = j >> 2, d0 = (j & 3) * 4;
            float* dst = ws + OFF_GEOK + (((size_t)(bt * 4 + h) * 512) + n) * 16 + d0;
            float4 old = *(float4*)dst;
            old.x += ax * inv; old.y += ay * inv; old.z += az * inv; old.w += aw * inv;
            *(float4*)dst = old;
        }
    }
}

// ---------------------------------------------------------------------------
// K4: spatial attention. One block per (b,t,head-instance); K,V in LDS (64KB);
// 256 threads x 2 rows; chunked online softmax (chunks of 16 cols).
// ---------------------------------------------------------------------------
__global__ __launch_bounds__(256, 2) void spatial_attn(float* __restrict__ ws) {
    __shared__ float ldsK[512][16];
    __shared__ float ldsV[512][16];
    int inst = blockIdx.x;
    int hg = inst & 7, bt = inst >> 3;
    size_t qoff, koff, voff;
    const uint32_t* mbase = (const uint32_t*)(ws + OFF_MB);
    const uint32_t* mb;
    int cbase;
    if (hg < 4) {
        size_t hb = ((size_t)bt * 4 + hg) * 8192;
        qoff = OFF_GEOQ + hb; koff = OFF_GEOK + hb; voff = OFF_GEOV + hb;
        mb = mbase; cbase = 32 + hg * 16;
    } else if (hg < 6) {
        int h = hg - 4; size_t hb = ((size_t)bt * 2 + h) * 8192;
        qoff = OFF_SEM + hb; koff = OFF_SEM + TSZ + hb; voff = OFF_SEM + 2 * TSZ + hb;
        mb = mbase + 8192; cbase = 96 + h * 16;
    } else {
        int h = hg - 6; size_t hb = ((size_t)bt * 2 + h) * 8192;
        qoff = OFF_RND + hb; koff = OFF_RND + TSZ + hb; voff = OFF_RND + 2 * TSZ + hb;
        mb = mbase + 16384; cbase = 128 + h * 16;
    }
    int t = threadIdx.x;
    {
        const float4* Kg = (const float4*)(ws + koff);
        const float4* Vg = (const float4*)(ws + voff);
        float4* k4 = (float4*)ldsK;
        float4* v4 = (float4*)ldsV;
        for (int f = t; f < 2048; f += 256) { k4[f] = Kg[f]; v4[f] = Vg[f]; }
    }
    __syncthreads();
    int n0 = t, n1 = t + 256;
    const float* Qg = ws + qoff;
    float q0[16], q1[16];
    #pragma unroll
    for (int j = 0; j < 4; j++) {
        float4 v = *(const float4*)(Qg + (size_t)n0 * 16 + j * 4);
        q0[j * 4 + 0] = v.x; q0[j * 4 + 1] = v.y; q0[j * 4 + 2] = v.z; q0[j * 4 + 3] = v.w;
        float4 w = *(const float4*)(Qg + (size_t)n1 * 16 + j * 4);
        q1[j * 4 + 0] = w.x; q1[j * 4 + 1] = w.y; q1[j * 4 + 2] = w.z; q1[j * 4 + 3] = w.w;
    }
    float acc0[16], acc1[16];
    #pragma unroll
    for (int d = 0; d < 16; d++) { acc0[d] = 0.f; acc1[d] = 0.f; }
    float mx0 = -3e38f, mx1 = -3e38f, l0 = 0.f, l1 = 0.f;
    for (int ch = 0; ch < 32; ch++) {
        uint32_t mw0 = mb[n0 * 16 + (ch >> 1)] >> ((ch & 1) * 16);
        uint32_t mw1 = mb[n1 * 16 + (ch >> 1)] >> ((ch & 1) * 16);
        float s0[16], s1[16];
        #pragma unroll
        for (int mm = 0; mm < 16; mm++) {
            int m = ch * 16 + mm;
            const float* kr = ldsK[m];
            float d0v = 0.f, d1v = 0.f;
            #pragma unroll
            for (int j = 0; j < 4; j++) {
                float4 k4 = *(const float4*)(kr + j * 4);
                d0v += q0[j*4+0]*k4.x + q0[j*4+1]*k4.y + q0[j*4+2]*k4.z + q0[j*4+3]*k4.w;
                d1v += q1[j*4+0]*k4.x + q1[j*4+1]*k4.y + q1[j*4+2]*k4.z + q1[j*4+3]*k4.w;
            }
            s0[mm] = ((mw0 >> mm) & 1) ? -1e30f : d0v * 0.25f;
            s1[mm] = ((mw1 >> mm) & 1) ? -1e30f : d1v * 0.25f;
        }
        float cm0 = s0[0], cm1 = s1[0];
        #pragma unroll
        for (int mm = 1; mm < 16; mm++) { cm0 = fmaxf(cm0, s0[mm]); cm1 = fmaxf(cm1, s1[mm]); }
        float nm0 = fmaxf(mx0, cm0), nm1 = fmaxf(mx1, cm1);
        float sc0 = __expf(mx0 - nm0), sc1 = __expf(mx1 - nm1);
        mx0 = nm0; mx1 = nm1; l0 *= sc0; l1 *= sc1;
        #pragma unroll
        for (int d = 0; d < 16; d++) { acc0[d] *= sc0; acc1[d] *= sc1; }
        #pragma unroll
        for (int mm = 0; mm < 16; mm++) {
            int m = ch * 16 + mm;
            float p0 = __expf(s0[mm] - mx0), p1 = __expf(s1[mm] - mx1);
            l0 += p0; l1 += p1;
            const float* vr = ldsV[m];
            #pragma unroll
            for (int j = 0; j < 4; j++) {
                float4 v4 = *(const float4*)(vr + j * 4);
                acc0[j*4+0] += p0*v4.x; acc0[j*4+1] += p0*v4.y; acc0[j*4+2] += p0*v4.z; acc0[j*4+3] += p0*v4.w;
                acc1[j*4+0] += p1*v4.x; acc1[j*4+1] += p1*v4.y; acc1[j*4+2] += p1*v4.z; acc1[j*4+3] += p1*v4.w;
            }
        }
    }
    float inv0 = 1.f / l0, inv1 = 1.f / l1;
    float* cat = ws + OFF_CAT;
    size_t ro0 = ((size_t)bt * 512 + n0) * 224 + cbase;
    size_t ro1 = ((size_t)bt * 512 + n1) * 224 + cbase;
    #pragma unroll
    for (int j = 0; j < 4; j++) {
        *(float4*)(cat + ro0 + j * 4) = make_float4(acc0[j*4]*inv0, acc0[j*4+1]*inv0, acc0[j*4+2]*inv0, acc0[j*4+3]*inv0);
        *(float4*)(cat + ro1 + j * 4) = make_float4(acc1[j*4]*inv1, acc1[j*4+1]*inv1, acc1[j*4+2]*inv1, acc1[j*4+3]*inv1);
    }
}

// ---------------------------------------------------------------------------
// K5: temporal attention (t-branch -> t_x & rt_x, tube-branch -> tube_x).
// One thread per (b,n,h,t).
// ---------------------------------------------------------------------------
__global__ __launch_bounds__(256, 4) void temporal_attn(float* __restrict__ ws) {
    int tid = blockIdx.x * 256 + threadIdx.x;   // 49152 total
    int tt = tid % 24;
    int h  = (tid / 24) & 1;
    int n  = (tid / 48) & 511;
    int b  = tid / 24576;
    size_t base = (((size_t)b * 512 + n) * 2 + h) * 384;
    const float* TQ  = ws + OFF_T0 + 0 * TSZ + base;
    const float* TK  = ws + OFF_T0 + 1 * TSZ + base;
    const float* TV  = ws + OFF_T0 + 2 * TSZ + base;
    const float* RTV = ws + OFF_T0 + 3 * TSZ + base;
    const float* UQ  = ws + OFF_T0 + 4 * TSZ + base;
    const float* UK  = ws + OFF_T0 + 5 * TSZ + base;
    const float* UV  = ws + OFF_T0 + 6 * TSZ + base;
    float* cat = ws + OFF_CAT + (((size_t)b * 24 + tt) * 512 + n) * 224;

    float q[16], p[24];
    // ---- t branch ----
    #pragma unroll
    for (int j = 0; j < 4; j++) {
        float4 v = *(const float4*)(TQ + tt * 16 + j * 4);
        q[j*4+0] = v.x; q[j*4+1] = v.y; q[j*4+2] = v.z; q[j*4+3] = v.w;
    }
    float mx = -3e38f;
    #pragma unroll
    for (int s = 0; s < 24; s++) {
        float d = 0.f;
        #pragma unroll
        for (int j = 0; j < 4; j++) {
            float4 k4 = *(const float4*)(TK + s * 16 + j * 4);
            d += q[j*4+0]*k4.x + q[j*4+1]*k4.y + q[j*4+2]*k4.z + q[j*4+3]*k4.w;
        }
        d *= 0.25f; p[s] = d; mx = fmaxf(mx, d);
    }
    float l = 0.f;
    #pragma unroll
    for (int s = 0; s < 24; s++) { p[s] = __expf(p[s] - mx); l += p[s]; }
    float inv = 1.f / l;
    float a1[16], a2[16];
    #pragma unroll
    for (int d = 0; d < 16; d++) { a1[d] = 0.f; a2[d] = 0.f; }
    #pragma unroll
    for (int s = 0; s < 24; s++) {
        float w = p[s];
        #pragma unroll
        for (int j = 0; j < 4; j++) {
            float4 v4 = *(const float4*)(TV + s * 16 + j * 4);
            a1[j*4+0] += w*v4.x; a1[j*4+1] += w*v4.y; a1[j*4+2] += w*v4.z; a1[j*4+3] += w*v4.w;
            float4 r4 = *(const float4*)(RTV + s * 16 + j * 4);
            a2[j*4+0] += w*r4.x; a2[j*4+1] += w*r4.y; a2[j*4+2] += w*r4.z; a2[j*4+3] += w*r4.w;
        }
    }
    #pragma unroll
    for (int j = 0; j < 4; j++) {
        *(float4*)(cat + 0 + h * 16 + j * 4)   = make_float4(a1[j*4]*inv, a1[j*4+1]*inv, a1[j*4+2]*inv, a1[j*4+3]*inv);
        *(float4*)(cat + 160 + h * 16 + j * 4) = make_float4(a2[j*4]*inv, a2[j*4+1]*inv, a2[j*4+2]*inv, a2[j*4+3]*inv);
    }
    // ---- tube branch ----
    #pragma unroll
    for (int j = 0; j < 4; j++) {
        float4 v = *(const float4*)(UQ + tt * 16 + j * 4);
        q[j*4+0] = v.x; q[j*4+1] = v.y; q[j*4+2] = v.z; q[j*4+3] = v.w;
    }
    mx = -3e38f;
    #pragma unroll
    for (int s = 0; s < 24; s++) {
        float d = 0.f;
        #pragma unroll
        for (int j = 0; j < 4; j++) {
            float4 k4 = *(const float4*)(UK + s * 16 + j * 4);
            d += q[j*4+0]*k4.x + q[j*4+1]*k4.y + q[j*4+2]*k4.z + q[j*4+3]*k4.w;
        }
        d *= 0.25f; p[s] = d; mx = fmaxf(mx, d);
    }
    l = 0.f;
    #pragma unroll
    for (int s = 0; s < 24; s++) { p[s] = __expf(p[s] - mx); l += p[s]; }
    inv = 1.f / l;
    #pragma unroll
    for (int d = 0; d < 16; d++) a1[d] = 0.f;
    #pragma unroll
    for (int s = 0; s < 24; s++) {
        float w = p[s];
        #pragma unroll
        for (int j = 0; j < 4; j++) {
            float4 v4 = *(const float4*)(UV + s * 16 + j * 4);
            a1[j*4+0] += w*v4.x; a1[j*4+1] += w*v4.y; a1[j*4+2] += w*v4.z; a1[j*4+3] += w*v4.w;
        }
    }
    #pragma unroll
    for (int j = 0; j < 4; j++)
        *(float4*)(cat + 192 + h * 16 + j * 4) = make_float4(a1[j*4]*inv, a1[j*4+1]*inv, a1[j*4+2]*inv, a1[j*4+3]*inv);
}

// ---------------------------------------------------------------------------
extern "C" void kernel_launch(void* const* d_in, const int* in_sizes, int n_in,
                              void* d_out, int out_size, void* d_ws, size_t ws_size,
                              hipStream_t stream) {
    const float* x     = (const float*)d_in[0];
    const float* xp    = (const float*)d_in[1];
    const float* pkeys = (const float*)d_in[2];
    float* ws  = (float*)d_ws;
    float* out = (float*)d_out;

    PackPtrs pp;
    pp.w[0]  = (const float*)d_in[6];   // t_wq
    pp.w[1]  = (const float*)d_in[7];   // t_wk
    pp.w[2]  = (const float*)d_in[8];   // t_wv
    pp.w[3]  = (const float*)d_in[24];  // rt_wv
    pp.w[4]  = (const float*)d_in[25];  // tube_wq
    pp.w[5]  = (const float*)d_in[26];  // tube_wk
    pp.w[6]  = (const float*)d_in[27];  // tube_wv
    pp.w[7]  = (const float*)d_in[9];   // geo_wq
    pp.w[8]  = (const float*)d_in[10];  // geo_wk
    pp.w[9]  = (const float*)d_in[11];  // geo_wv
    pp.w[10] = (const float*)d_in[18];  // sem_wq
    pp.w[11] = (const float*)d_in[19];  // sem_wk
    pp.w[12] = (const float*)d_in[20];  // sem_wv
    pp.w[13] = (const float*)d_in[21];  // rnd_wq
    pp.w[14] = (const float*)d_in[22];  // rnd_wk
    pp.w[15] = (const float*)d_in[23];  // rnd_wv
    pp.msk[0] = d_in[3];
    pp.msk[1] = d_in[4];
    pp.msk[2] = d_in[5];

    pack_kernel<<<dim3(416), dim3(256), 0, stream>>>(pp, ws);
    proj_gemm<<<dim3(384, 2), dim3(256), 0, stream>>>(x, ws);
    gemm_tile<<<dim3(384, 1), dim3(256), 0, stream>>>(xp, (const float*)d_in[12],
              (const float*)d_in[13], ws + OFF_PQ, 128, 64);
    gemm_tile<<<dim3(12, 1), dim3(256), 0, stream>>>(pkeys, (const float*)d_in[14],
              (const float*)d_in[15], ws + OFF_PK, 128, 64);
    gemm_tile<<<dim3(12, 1), dim3(256), 0, stream>>>(pkeys, (const float*)d_in[16],
              (const float*)d_in[17], ws + OFF_PV, 128, 64);
    pattern_attn<<<dim3(48), dim3(256), 0, stream>>>(ws);
    spatial_attn<<<dim3(384), dim3(256), 0, stream>>>(ws);
    temporal_attn<<<dim3(192), dim3(256), 0, stream>>>(ws);
    gemm_tile<<<dim3(384, 2), dim3(256), 0, stream>>>(ws + OFF_CAT, (const float*)d_in[28],
              (const float*)d_in[29], out, 224, 128);
}

// Round 8
// 424.485 us; speedup vs baseline: 1.2960x; 1.2960x over previous
//
#include <hip/hip_runtime.h>
#include <stdint.h>

// Problem constants
// B=2, T=24, N=512, D=128, P=16, HD=16; SCALE=0.25
// temporal arrays layout [B,N,2,24,16]; spatial [B,T,H,N,16]

static const size_t OFF_WP   = 0;                      // packed weights [128][640]
static const size_t TSZ      = 786432;                 // 2*512*2*24*16
static const size_t GSZ      = 1572864;                // 2*24*4*512*16
static const size_t OFF_T0   = 81920;                  // 7 temporal arrays (tq,tk,tv,rtv,tubq,tubk,tubv)
static const size_t OFF_GEOQ = OFF_T0 + 7*TSZ;         // geo q,k,v each GSZ
static const size_t OFF_GEOK = OFF_GEOQ + GSZ;
static const size_t OFF_GEOV = OFF_GEOK + GSZ;
static const size_t OFF_SEM  = OFF_GEOQ + 3*GSZ;       // sem q,k,v each TSZ
static const size_t OFF_RND  = OFF_SEM + 3*TSZ;        // rnd q,k,v each TSZ
static const size_t OFF_PQ   = OFF_RND + 3*TSZ;        // [24576][64]
static const size_t OFF_PK   = OFF_PQ + GSZ;           // [768][64]
static const size_t OFF_PV   = OFF_PK + 49152;
static const size_t OFF_CAT  = OFF_PV + 49152;         // [24576][224]
static const size_t OFF_MB   = OFF_CAT + 24576ull*224; // 3*512*16 u32 mask words

using f32x4 = __attribute__((ext_vector_type(4))) float;
using f16x4 = __attribute__((ext_vector_type(4))) _Float16;

struct PackPtrs {
    const float* w[16];
    const void* msk[3];
};

// ---------------------------------------------------------------------------
// K0: pack weights into [128][640] (zero-pad cols 608..639) + bit-pack masks.
// Mask buffers (jnp bool) may arrive as uint8 (1B/elem), int32 (0/1), or
// float32 (0.0/1.0). For BOTH 4-byte encodings, "word != 0" decodes truth, so
// we only distinguish 4-byte vs 1-byte: scan 64 words — float32 signature
// (every word in {0, 0x3F800000}) OR int32 signature (bytes 1..3 always 0)
// => word-decode; else byte-decode. P(misclassify | random 0.5 bools) ~ 8^-64.
// ---------------------------------------------------------------------------
__global__ __launch_bounds__(256) void pack_kernel(PackPtrs pp, float* __restrict__ ws) {
    int tid = blockIdx.x * 256 + threadIdx.x;
    if (tid < 128 * 640) {
        int k = tid / 640, c = tid % 640;
        float v = 0.f;
        if (c < 608) {
            if (c < 224) {              // 7 temporal mats, each D x 32
                int which = c >> 5, col = c & 31;
                v = pp.w[which][k * 32 + col];
            } else if (c < 416) {       // geo q,k,v, each D x 64
                int cc = c - 224; int which = 7 + (cc >> 6), col = cc & 63;
                v = pp.w[which][k * 64 + col];
            } else {                    // sem q,k,v + rnd q,k,v, each D x 32
                int cc = c - 416; int which = 10 + (cc >> 5), col = cc & 31;
                v = pp.w[which][k * 32 + col];
            }
        }
        ws[OFF_WP + tid] = v;
    } else {
        int w = tid - 128 * 640;
        if (w < 3 * 8192) {
            int mi = w / 8192, rem = w % 8192;
            int base = (rem >> 4) * 512 + (rem & 15) * 32;   // element index of bit 0
            const uint32_t* w32 = (const uint32_t*)pp.msk[mi];
            uint32_t hibytes = 0;      // nonzero => not int32 0/1
            int isfloat = 1;           // stays 1 => every word is 0.0f or 1.0f
            #pragma unroll
            for (int i = 0; i < 64; i++) {
                uint32_t wv = w32[i];
                hibytes |= wv & 0xFFFFFF00u;
                if (wv != 0u && wv != 0x3F800000u) isfloat = 0;
            }
            uint32_t bits = 0;
            if (isfloat || hibytes == 0) {   // 4-byte elements: word != 0 is truth
                const uint32_t* s = w32 + base;
                #pragma unroll
                for (int j = 0; j < 32; j++) bits |= (s[j] != 0u ? 1u : 0u) << j;
            } else {                          // 1-byte elements
                const uint8_t* s = (const uint8_t*)pp.msk[mi] + base;
                #pragma unroll
                for (int j = 0; j < 32; j++) bits |= (s[j] ? 1u : 0u) << j;
            }
            ((uint32_t*)(ws + OFF_MB))[w] = bits;
        }
    }
}

// ---------------------------------------------------------------------------
// K1: projection GEMM x[24576x128] @ Wp[128x608] with scatter epilogue.
// ---------------------------------------------------------------------------
__global__ __launch_bounds__(256, 4) void proj_gemm(const float* __restrict__ x,
                                                    float* __restrict__ ws) {
    __shared__ float a_t[128][68];
    int rb = blockIdx.x * 64;
    int t = threadIdx.x;
    for (int f = t; f < 64 * 32; f += 256) {   // 2048 float4 loads
        int r = f >> 5, kc = f & 31;
        float4 v = *(const float4*)(x + (size_t)(rb + r) * 128 + kc * 4);
        a_t[kc * 4 + 0][r] = v.x; a_t[kc * 4 + 1][r] = v.y;
        a_t[kc * 4 + 2][r] = v.z; a_t[kc * 4 + 3][r] = v.w;
    }
    __syncthreads();
    int tr = t & 15, tc = t >> 4;
    int r0 = tr * 4, c0 = tc * 4;
    int rn[4], rt_[4], rbq[4];
    #pragma unroll
    for (int i = 0; i < 4; i++) {
        int row = rb + r0 + i;
        rn[i] = row & 511;
        int bt = row >> 9;
        rt_[i] = bt % 24; rbq[i] = bt / 24;
    }
    const float* Wp = ws + OFF_WP;
    for (int ct = blockIdx.y * 5; ct < (int)blockIdx.y * 5 + 5; ct++) {
        float acc[4][4] = {{0.f}};
        int cg = ct * 64 + c0;
        const float* wcol = Wp + cg;
        #pragma unroll 8
        for (int k = 0; k < 128; k++) {
            float4 a4 = *(const float4*)&a_t[k][r0];
            float4 b4 = *(const float4*)(wcol + (size_t)k * 640);
            float av[4] = {a4.x, a4.y, a4.z, a4.w};
            float bv[4] = {b4.x, b4.y, b4.z, b4.w};
            #pragma unroll
            for (int i = 0; i < 4; i++)
                #pragma unroll
                for (int j = 0; j < 4; j++) acc[i][j] += av[i] * bv[j];
        }
        if (cg < 608) {
            int d0 = cg & 15;
            #pragma unroll
            for (int i = 0; i < 4; i++) {
                size_t idx;
                if (cg < 224) {
                    int which = cg >> 5, h = (cg >> 4) & 1;
                    idx = OFF_T0 + (size_t)which * TSZ +
                          ((((size_t)rbq[i] * 512 + rn[i]) * 2 + h) * 24 + rt_[i]) * 16 + d0;
                } else if (cg < 416) {
                    int cc = cg - 224, g = cc >> 6, h = (cc >> 4) & 3;
                    idx = OFF_GEOQ + (size_t)g * GSZ +
                          (((size_t)(rbq[i] * 24 + rt_[i]) * 4 + h) * 512 + rn[i]) * 16 + d0;
                } else {
                    int cc = cg - 416; int isr = cc >= 96 ? 1 : 0; cc -= isr * 96;
                    int g = cc >> 5, h = (cc >> 4) & 1;
                    idx = (isr ? OFF_RND : OFF_SEM) + (size_t)g * TSZ +
                          (((size_t)(rbq[i] * 24 + rt_[i]) * 2 + h) * 512 + rn[i]) * 16 + d0;
                }
                *(float4*)(ws + idx) = make_float4(acc[i][0], acc[i][1], acc[i][2], acc[i][3]);
            }
        }
    }
}

// ---------------------------------------------------------------------------
// Generic tiled GEMM: C[M][N] = A[M][K] @ W[K][N] (+bias). BM=BN=64, KT=32.
// ---------------------------------------------------------------------------
__global__ __launch_bounds__(256, 4) void gemm_tile(const float* __restrict__ A,
                                                    const float* __restrict__ W,
                                                    const float* __restrict__ bias,
                                                    float* __restrict__ C,
                                                    int K, int N) {
    __shared__ float a_t[32][68];
    __shared__ float bs[32][64];
    int rb = blockIdx.x * 64, cb = blockIdx.y * 64;
    int t = threadIdx.x, tr = t & 15, tc = t >> 4;
    float acc[4][4] = {{0.f}};
    for (int k0 = 0; k0 < K; k0 += 32) {
        __syncthreads();
        for (int f = t; f < 512; f += 256) {
            int r = f >> 3, kc = f & 7;
            float4 v = *(const float4*)(A + (size_t)(rb + r) * K + k0 + kc * 4);
            a_t[kc * 4 + 0][r] = v.x; a_t[kc * 4 + 1][r] = v.y;
            a_t[kc * 4 + 2][r] = v.z; a_t[kc * 4 + 3][r] = v.w;
        }
        for (int f = t; f < 512; f += 256) {
            int kk = f >> 4, cc = f & 15;
            *(float4*)&bs[kk][cc * 4] = *(const float4*)(W + (size_t)(k0 + kk) * N + cb + cc * 4);
        }
        __syncthreads();
        #pragma unroll
        for (int kk = 0; kk < 32; kk++) {
            float4 a4 = *(const float4*)&a_t[kk][tr * 4];
            float4 b4 = *(const float4*)&bs[kk][tc * 4];
            float av[4] = {a4.x, a4.y, a4.z, a4.w};
            float bv[4] = {b4.x, b4.y, b4.z, b4.w};
            #pragma unroll
            for (int i = 0; i < 4; i++)
                #pragma unroll
                for (int j = 0; j < 4; j++) acc[i][j] += av[i] * bv[j];
        }
    }
    #pragma unroll
    for (int i = 0; i < 4; i++) {
        int row = rb + tr * 4 + i, col = cb + tc * 4;
        float4 o = make_float4(acc[i][0], acc[i][1], acc[i][2], acc[i][3]);
        if (bias) {
            o.x += bias[col]; o.y += bias[col + 1];
            o.z += bias[col + 2]; o.w += bias[col + 3];
        }
        *(float4*)(C + (size_t)row * N + col) = o;
    }
}

// ---------------------------------------------------------------------------
// K3: pattern attention; k_add accumulated into geo_K.
// ---------------------------------------------------------------------------
__global__ __launch_bounds__(256, 4) void pattern_attn(float* __restrict__ ws) {
    __shared__ float pk[16][64];
    __shared__ float pv[16][64];
    int bt = blockIdx.x, t = threadIdx.x;
    {
        int p = t >> 4, cc = t & 15;
        *(float4*)&pk[p][cc * 4] = *(const float4*)(ws + OFF_PK + (size_t)bt * 1024 + p * 64 + cc * 4);
        *(float4*)&pv[p][cc * 4] = *(const float4*)(ws + OFF_PV + (size_t)bt * 1024 + p * 64 + cc * 4);
    }
    __syncthreads();
    for (int rr = 0; rr < 2; rr++) {
        int n = t + rr * 256;
        const float* pqr = ws + OFF_PQ + ((size_t)bt * 512 + n) * 64;
        float s[16];
        #pragma unroll
        for (int p = 0; p < 16; p++) s[p] = 0.f;
        #pragma unroll
        for (int j = 0; j < 16; j++) {
            float4 q4 = *(const float4*)(pqr + j * 4);
            #pragma unroll
            for (int p = 0; p < 16; p++) {
                float4 k4 = *(const float4*)&pk[p][j * 4];
                s[p] += q4.x * k4.x + q4.y * k4.y + q4.z * k4.z + q4.w * k4.w;
            }
        }
        float mx = -3e38f;
        #pragma unroll
        for (int p = 0; p < 16; p++) { s[p] *= 0.25f; mx = fmaxf(mx, s[p]); }
        float l = 0.f;
        #pragma unroll
        for (int p = 0; p < 16; p++) { s[p] = __expf(s[p] - mx); l += s[p]; }
        float inv = 1.f / l;
        #pragma unroll
        for (int j = 0; j < 16; j++) {
            float ax = 0.f, ay = 0.f, az = 0.f, aw = 0.f;
            #pragma unroll
            for (int p = 0; p < 16; p++) {
                float4 v4 = *(const float4*)&pv[p][j * 4];
                ax += s[p] * v4.x; ay += s[p] * v4.y; az += s[p] * v4.z; aw += s[p] * v4.w;
            }
            int h = j >> 2, d0 = (j & 3) * 4;
            float* dst = ws + OFF_GEOK + (((size_t)(bt * 4 + h) * 512) + n) * 16 + d0;
            float4 old = *(float4*)dst;
            old.x += ax * inv; old.y += ay * inv; old.z += az * inv; old.w += aw * inv;
            *(float4*)dst = old;
        }
    }
}

// ---------------------------------------------------------------------------
// K4 (MFMA): spatial attention via v_mfma_f32_16x16x16_f16, swapped-operand
// trick: S^T tile = mfma(A=K_tile, B=Q_tile); the S^T C-fragment is exactly
// the A-fragment of P for the PV mfma (lane q = l&15 -> softmax is lane-local,
// 2 shfl_xor per reduce). K/V staged in LDS as pre-swizzled f16 frag slots
// (slot[ct*64+lane], 8B/lane ds_read_b64, conflict-free). Online softmax over
// 4 chunks of 128 cols. 2 blocks per (b,t,head) instance (256 q-rows each);
// grid 768 = 3 blocks/CU; LDS 32KB.
// ---------------------------------------------------------------------------
__global__ __launch_bounds__(256) void spatial_attn_mfma(float* __restrict__ ws) {
    __shared__ uint2 ldsK[2048];  // slot[ct*64+l] = K[ct*16+(l&15)][(l>>4)*4+0..3] f16
    __shared__ uint2 ldsV[2048];  // slot[ct*64+l] = V[ct*16+(l>>4)*4+0..3][l&15] f16
    int blk = blockIdx.x;
    int inst = blk >> 1, qhalf = blk & 1;
    int hg = inst & 7, bt = inst >> 3;
    size_t qoff, koff, voff;
    const uint32_t* mbase = (const uint32_t*)(ws + OFF_MB);
    const uint32_t* mb;
    int cbase;
    if (hg < 4) {
        size_t hb = ((size_t)bt * 4 + hg) * 8192;
        qoff = OFF_GEOQ + hb; koff = OFF_GEOK + hb; voff = OFF_GEOV + hb;
        mb = mbase; cbase = 32 + hg * 16;
    } else if (hg < 6) {
        int h = hg - 4; size_t hb = ((size_t)bt * 2 + h) * 8192;
        qoff = OFF_SEM + hb; koff = OFF_SEM + TSZ + hb; voff = OFF_SEM + 2 * TSZ + hb;
        mb = mbase + 8192; cbase = 96 + h * 16;
    } else {
        int h = hg - 6; size_t hb = ((size_t)bt * 2 + h) * 8192;
        qoff = OFF_RND + hb; koff = OFF_RND + TSZ + hb; voff = OFF_RND + 2 * TSZ + hb;
        mb = mbase + 16384; cbase = 128 + h * 16;
    }
    int t = threadIdx.x;
    // --- stage K (A-frag layout) ---
    {
        const float* Kg = ws + koff;
        for (int s = t; s < 2048; s += 256) {
            int l = s & 63;
            int row = ((s >> 6) << 4) + (l & 15), dg = (l >> 4) * 4;
            float4 v = *(const float4*)(Kg + (size_t)row * 16 + dg);
            f16x4 h;
            h[0] = (_Float16)v.x; h[1] = (_Float16)v.y;
            h[2] = (_Float16)v.z; h[3] = (_Float16)v.w;
            ldsK[s] = *(uint2*)&h;
        }
    }
    // --- stage V (B-frag layout: k-transposed) ---
    {
        const float* Vg = ws + voff;
        for (int s = t; s < 2048; s += 256) {
            int l = s & 63;
            int dcol = l & 15, rb = ((s >> 6) << 4) + (l >> 4) * 4;
            f16x4 h;
            h[0] = (_Float16)Vg[(size_t)(rb + 0) * 16 + dcol];
            h[1] = (_Float16)Vg[(size_t)(rb + 1) * 16 + dcol];
            h[2] = (_Float16)Vg[(size_t)(rb + 2) * 16 + dcol];
            h[3] = (_Float16)Vg[(size_t)(rb + 3) * 16 + dcol];
            ldsV[s] = *(uint2*)&h;
        }
    }
    __syncthreads();
    int lane = t & 63, wave = t >> 6;
    int lq = lane & 15, lg = lane >> 4;
    const float* Qg = ws + qoff;
    float* cat = ws + OFF_CAT;
    const f32x4 zero4 = {0.f, 0.f, 0.f, 0.f};
    for (int jt = 0; jt < 4; jt++) {
        int qt = qhalf * 16 + wave * 4 + jt;   // global q-tile 0..31
        int q = qt * 16 + lq;                  // this lane's softmax row
        float4 qv = *(const float4*)(Qg + (size_t)q * 16 + lg * 4);
        f16x4 qf;                              // pre-scaled by SCALE=0.25
        qf[0] = (_Float16)(qv.x * 0.25f); qf[1] = (_Float16)(qv.y * 0.25f);
        qf[2] = (_Float16)(qv.z * 0.25f); qf[3] = (_Float16)(qv.w * 0.25f);
        f32x4 O = zero4;
        float m = -3e38f, lsum = 0.f;
        const uint32_t* mrow = mb + (size_t)q * 16;
        for (int ch = 0; ch < 4; ch++) {
            uint4 mw = *(const uint4*)(mrow + ch * 4);
            float p[8][4];
            float cm = -3e38f;
            #pragma unroll
            for (int c8 = 0; c8 < 8; c8++) {
                int ct = ch * 8 + c8;
                uint2 kslot = ldsK[ct * 64 + lane];
                f16x4 kf = *(f16x4*)&kslot;
                f32x4 sres = __builtin_amdgcn_mfma_f32_16x16x16f16(kf, qf, zero4, 0, 0, 0);
                uint32_t w = ((const uint32_t*)&mw)[c8 >> 1];
                uint32_t nib = (w >> (((c8 & 1) << 4) + lg * 4)) & 0xFu;
                #pragma unroll
                for (int i = 0; i < 4; i++) {
                    float sv = ((nib >> i) & 1u) ? -1e30f : sres[i];
                    p[c8][i] = sv;
                    cm = fmaxf(cm, sv);
                }
            }
            cm = fmaxf(cm, __shfl_xor(cm, 16));
            cm = fmaxf(cm, __shfl_xor(cm, 32));
            float nm = fmaxf(m, cm);
            float scale = __expf(m - nm);
            m = nm;
            float psum = 0.f;
            #pragma unroll
            for (int c8 = 0; c8 < 8; c8++)
                #pragma unroll
                for (int i = 0; i < 4; i++) {
                    float pv = __expf(p[c8][i] - m);
                    p[c8][i] = pv; psum += pv;
                }
            lsum = lsum * scale + psum;
            #pragma unroll
            for (int i = 0; i < 4; i++) O[i] *= __shfl(scale, lg * 4 + i);
            #pragma unroll
            for (int c8 = 0; c8 < 8; c8++) {
                int ct = ch * 8 + c8;
                f16x4 pf;
                pf[0] = (_Float16)p[c8][0]; pf[1] = (_Float16)p[c8][1];
                pf[2] = (_Float16)p[c8][2]; pf[3] = (_Float16)p[c8][3];
                uint2 vslot = ldsV[ct * 64 + lane];
                f16x4 vf = *(f16x4*)&vslot;
                O = __builtin_amdgcn_mfma_f32_16x16x16f16(pf, vf, O, 0, 0, 0);
            }
        }
        lsum += __shfl_xor(lsum, 16);
        lsum += __shfl_xor(lsum, 32);
        #pragma unroll
        for (int i = 0; i < 4; i++) {
            float ls = __shfl(lsum, lg * 4 + i);
            int qrow = qt * 16 + lg * 4 + i;
            cat[((size_t)bt * 512 + qrow) * 224 + cbase + lq] = O[i] / ls;
        }
    }
}

// ---------------------------------------------------------------------------
// K5: temporal attention (t-branch -> t_x & rt_x, tube-branch -> tube_x).
// ---------------------------------------------------------------------------
__global__ __launch_bounds__(256, 4) void temporal_attn(float* __restrict__ ws) {
    int tid = blockIdx.x * 256 + threadIdx.x;   // 49152 total
    int tt = tid % 24;
    int h  = (tid / 24) & 1;
    int n  = (tid / 48) & 511;
    int b  = tid / 24576;
    size_t base = (((size_t)b * 512 + n) * 2 + h) * 384;
    const float* TQ  = ws + OFF_T0 + 0 * TSZ + base;
    const float* TK  = ws + OFF_T0 + 1 * TSZ + base;
    const float* TV  = ws + OFF_T0 + 2 * TSZ + base;
    const float* RTV = ws + OFF_T0 + 3 * TSZ + base;
    const float* UQ  = ws + OFF_T0 + 4 * TSZ + base;
    const float* UK  = ws + OFF_T0 + 5 * TSZ + base;
    const float* UV  = ws + OFF_T0 + 6 * TSZ + base;
    float* cat = ws + OFF_CAT + (((size_t)b * 24 + tt) * 512 + n) * 224;

    float q[16], p[24];
    // ---- t branch ----
    #pragma unroll
    for (int j = 0; j < 4; j++) {
        float4 v = *(const float4*)(TQ + tt * 16 + j * 4);
        q[j*4+0] = v.x; q[j*4+1] = v.y; q[j*4+2] = v.z; q[j*4+3] = v.w;
    }
    float mx = -3e38f;
    #pragma unroll
    for (int s = 0; s < 24; s++) {
        float d = 0.f;
        #pragma unroll
        for (int j = 0; j < 4; j++) {
            float4 k4 = *(const float4*)(TK + s * 16 + j * 4);
            d += q[j*4+0]*k4.x + q[j*4+1]*k4.y + q[j*4+2]*k4.z + q[j*4+3]*k4.w;
        }
        d *= 0.25f; p[s] = d; mx = fmaxf(mx, d);
    }
    float l = 0.f;
    #pragma unroll
    for (int s = 0; s < 24; s++) { p[s] = __expf(p[s] - mx); l += p[s]; }
    float inv = 1.f / l;
    float a1[16], a2[16];
    #pragma unroll
    for (int d = 0; d < 16; d++) { a1[d] = 0.f; a2[d] = 0.f; }
    #pragma unroll
    for (int s = 0; s < 24; s++) {
        float w = p[s];
        #pragma unroll
        for (int j = 0; j < 4; j++) {
            float4 v4 = *(const float4*)(TV + s * 16 + j * 4);
            a1[j*4+0] += w*v4.x; a1[j*4+1] += w*v4.y; a1[j*4+2] += w*v4.z; a1[j*4+3] += w*v4.w;
            float4 r4 = *(const float4*)(RTV + s * 16 + j * 4);
            a2[j*4+0] += w*r4.x; a2[j*4+1] += w*r4.y; a2[j*4+2] += w*r4.z; a2[j*4+3] += w*r4.w;
        }
    }
    #pragma unroll
    for (int j = 0; j < 4; j++) {
        *(float4*)(cat + 0 + h * 16 + j * 4)   = make_float4(a1[j*4]*inv, a1[j*4+1]*inv, a1[j*4+2]*inv, a1[j*4+3]*inv);
        *(float4*)(cat + 160 + h * 16 + j * 4) = make_float4(a2[j*4]*inv, a2[j*4+1]*inv, a2[j*4+2]*inv, a2[j*4+3]*inv);
    }
    // ---- tube branch ----
    #pragma unroll
    for (int j = 0; j < 4; j++) {
        float4 v = *(const float4*)(UQ + tt * 16 + j * 4);
        q[j*4+0] = v.x; q[j*4+1] = v.y; q[j*4+2] = v.z; q[j*4+3] = v.w;
    }
    mx = -3e38f;
    #pragma unroll
    for (int s = 0; s < 24; s++) {
        float d = 0.f;
        #pragma unroll
        for (int j = 0; j < 4; j++) {
            float4 k4 = *(const float4*)(UK + s * 16 + j * 4);
            d += q[j*4+0]*k4.x + q[j*4+1]*k4.y + q[j*4+2]*k4.z + q[j*4+3]*k4.w;
        }
        d *= 0.25f; p[s] = d; mx = fmaxf(mx, d);
    }
    l = 0.f;
    #pragma unroll
    for (int s = 0; s < 24; s++) { p[s] = __expf(p[s] - mx); l += p[s]; }
    inv = 1.f / l;
    #pragma unroll
    for (int d = 0; d < 16; d++) a1[d] = 0.f;
    #pragma unroll
    for (int s = 0; s < 24; s++) {
        float w = p[s];
        #pragma unroll
        for (int j = 0; j < 4; j++) {
            float4 v4 = *(const float4*)(UV + s * 16 + j * 4);
            a1[j*4+0] += w*v4.x; a1[j*4+1] += w*v4.y; a1[j*4+2] += w*v4.z; a1[j*4+3] += w*v4.w;
        }
    }
    #pragma unroll
    for (int j = 0; j < 4; j++)
        *(float4*)(cat + 192 + h * 16 + j * 4) = make_float4(a1[j*4]*inv, a1[j*4+1]*inv, a1[j*4+2]*inv, a1[j*4+3]*inv);
}

// ---------------------------------------------------------------------------
extern "C" void kernel_launch(void* const* d_in, const int* in_sizes, int n_in,
                              void* d_out, int out_size, void* d_ws, size_t ws_size,
                              hipStream_t stream) {
    const float* x     = (const float*)d_in[0];
    const float* xp    = (const float*)d_in[1];
    const float* pkeys = (const float*)d_in[2];
    float* ws  = (float*)d_ws;
    float* out = (float*)d_out;

    PackPtrs pp;
    pp.w[0]  = (const float*)d_in[6];   // t_wq
    pp.w[1]  = (const float*)d_in[7];   // t_wk
    pp.w[2]  = (const float*)d_in[8];   // t_wv
    pp.w[3]  = (const float*)d_in[24];  // rt_wv
    pp.w[4]  = (const float*)d_in[25];  // tube_wq
    pp.w[5]  = (const float*)d_in[26];  // tube_wk
    pp.w[6]  = (const float*)d_in[27];  // tube_wv
    pp.w[7]  = (const float*)d_in[9];   // geo_wq
    pp.w[8]  = (const float*)d_in[10];  // geo_wk
    pp.w[9]  = (const float*)d_in[11];  // geo_wv
    pp.w[10] = (const float*)d_in[18];  // sem_wq
    pp.w[11] = (const float*)d_in[19];  // sem_wk
    pp.w[12] = (const float*)d_in[20];  // sem_wv
    pp.w[13] = (const float*)d_in[21];  // rnd_wq
    pp.w[14] = (const float*)d_in[22];  // rnd_wk
    pp.w[15] = (const float*)d_in[23];  // rnd_wv
    pp.msk[0] = d_in[3];
    pp.msk[1] = d_in[4];
    pp.msk[2] = d_in[5];

    pack_kernel<<<dim3(416), dim3(256), 0, stream>>>(pp, ws);
    proj_gemm<<<dim3(384, 2), dim3(256), 0, stream>>>(x, ws);
    gemm_tile<<<dim3(384, 1), dim3(256), 0, stream>>>(xp, (const float*)d_in[12],
              (const float*)d_in[13], ws + OFF_PQ, 128, 64);
    gemm_tile<<<dim3(12, 1), dim3(256), 0, stream>>>(pkeys, (const float*)d_in[14],
              (const float*)d_in[15], ws + OFF_PK, 128, 64);
    gemm_tile<<<dim3(12, 1), dim3(256), 0, stream>>>(pkeys, (const float*)d_in[16],
              (const float*)d_in[17], ws + OFF_PV, 128, 64);
    pattern_attn<<<dim3(48), dim3(256), 0, stream>>>(ws);
    spatial_attn_mfma<<<dim3(768), dim3(256), 0, stream>>>(ws);
    temporal_attn<<<dim3(192), dim3(256), 0, stream>>>(ws);
    gemm_tile<<<dim3(384, 2), dim3(256), 0, stream>>>(ws + OFF_CAT, (const float*)d_in[28],
              (const float*)d_in[29], out, 224, 128);
}

// Round 9
// 312.697 us; speedup vs baseline: 1.7593x; 1.3575x over previous
//
#include <hip/hip_runtime.h>
#include <stdint.h>

// Problem constants
// B=2, T=24, N=512, D=128, P=16, HD=16; SCALE=0.25
// temporal arrays layout [B,N,2,24,16]; spatial [B,T,H,N,16]

static const size_t OFF_WP   = 0;                      // f16 B-frag weights: uint2[40*8*64]
static const size_t TSZ      = 786432;                 // 2*512*2*24*16
static const size_t GSZ      = 1572864;                // 2*24*4*512*16
static const size_t OFF_T0   = 81920;                  // 7 temporal arrays (tq,tk,tv,rtv,tubq,tubk,tubv)
static const size_t OFF_GEOQ = OFF_T0 + 7*TSZ;         // geo q,k,v each GSZ
static const size_t OFF_GEOK = OFF_GEOQ + GSZ;
static const size_t OFF_GEOV = OFF_GEOK + GSZ;
static const size_t OFF_SEM  = OFF_GEOQ + 3*GSZ;       // sem q,k,v each TSZ
static const size_t OFF_RND  = OFF_SEM + 3*TSZ;        // rnd q,k,v each TSZ
static const size_t OFF_PQ   = OFF_RND + 3*TSZ;        // [24576][64]; becomes k_add in-place
static const size_t OFF_PK   = OFF_PQ + GSZ;           // [768][64]
static const size_t OFF_PV   = OFF_PK + 49152;
static const size_t OFF_CAT  = OFF_PV + 49152;         // [24576][224]
static const size_t OFF_MB   = OFF_CAT + 24576ull*224; // 3*512*16 u32 mask words

using f32x4 = __attribute__((ext_vector_type(4))) float;
using f16x4 = __attribute__((ext_vector_type(4))) _Float16;

struct PackPtrs {
    const float* w[16];
    const void* msk[3];
};

// ---------------------------------------------------------------------------
// K0: pack weights as f16 MFMA B-fragments wb[(nt*8+kt)*64 + lane] =
// {Wp[kt*16+(l>>4)*4+i][nt*16+(l&15)]}  (validated B-frag layout) + bit-pack
// masks (4-byte vs 1-byte encoding sniff, validated round 5).
// ---------------------------------------------------------------------------
__global__ __launch_bounds__(256) void pack_kernel(PackPtrs pp, float* __restrict__ ws) {
    int tid = blockIdx.x * 256 + threadIdx.x;
    if (tid < 20480) {
        int l = tid & 63, kt = (tid >> 6) & 7, nt = tid >> 9;
        int k0 = kt * 16 + ((l >> 4) << 2);
        int c  = nt * 16 + (l & 15);
        f16x4 h;
        #pragma unroll
        for (int i = 0; i < 4; i++) {
            float v = 0.f;
            int kk = k0 + i;
            if (c < 224) {              // 7 temporal mats, each D x 32
                int which = c >> 5, col = c & 31;
                v = pp.w[which][kk * 32 + col];
            } else if (c < 416) {       // geo q,k,v, each D x 64
                int cc = c - 224; int which = 7 + (cc >> 6), col = cc & 63;
                v = pp.w[which][kk * 64 + col];
            } else if (c < 608) {       // sem q,k,v + rnd q,k,v, each D x 32
                int cc = c - 416; int which = 10 + (cc >> 5), col = cc & 31;
                v = pp.w[which][kk * 32 + col];
            }
            h[i] = (_Float16)v;
        }
        ((uint2*)(ws + OFF_WP))[tid] = *(uint2*)&h;
    } else {
        int w = tid - 20480;
        if (w < 3 * 8192) {
            int mi = w / 8192, rem = w % 8192;
            int base = (rem >> 4) * 512 + (rem & 15) * 32;   // element index of bit 0
            const uint32_t* w32 = (const uint32_t*)pp.msk[mi];
            uint32_t hibytes = 0;      // nonzero => not int32 0/1
            int isfloat = 1;           // stays 1 => every word is 0.0f or 1.0f
            #pragma unroll
            for (int i = 0; i < 64; i++) {
                uint32_t wv = w32[i];
                hibytes |= wv & 0xFFFFFF00u;
                if (wv != 0u && wv != 0x3F800000u) isfloat = 0;
            }
            uint32_t bits = 0;
            if (isfloat || hibytes == 0) {   // 4-byte elements: word != 0 is truth
                const uint32_t* s = w32 + base;
                #pragma unroll
                for (int j = 0; j < 32; j++) bits |= (s[j] != 0u ? 1u : 0u) << j;
            } else {                          // 1-byte elements
                const uint8_t* s = (const uint8_t*)pp.msk[mi] + base;
                #pragma unroll
                for (int j = 0; j < 32; j++) bits |= (s[j] ? 1u : 0u) << j;
            }
            ((uint32_t*)(ws + OFF_MB))[w] = bits;
        }
    }
}

// ---------------------------------------------------------------------------
// K1 (MFMA): projection x[24576x128] @ W[128x608] -> scatter.
// Block: 64 rows (one bt), 4 waves; wave w covers col-tiles nt = w*10..w*10+9
// (nt>=38 is pad, skipped). A-frags loaded per-lane from x (f32->f16), B-frags
// from packed wb (coalesced 8B/lane). fp32 accumulate; scalar-f32 scatter
// (each nt is exactly one head slice; d0 = lane&15).
// ---------------------------------------------------------------------------
__global__ __launch_bounds__(256) void proj_gemm_mfma(const float* __restrict__ x,
                                                      float* __restrict__ ws) {
    int rb = blockIdx.x * 64;
    int t = threadIdx.x, lane = t & 63, w = t >> 6;
    int lr = lane & 15, lg4 = (lane >> 4) * 4;
    int bt = rb >> 9;                   // block-uniform
    int rt_ = bt % 24, rbq = bt / 24;
    int rnb = (rb & 511) + lg4;         // rn = rnb + rt*16 + i

    f16x4 af[4][8];
    #pragma unroll
    for (int rt = 0; rt < 4; rt++)
        #pragma unroll
        for (int kt = 0; kt < 8; kt++) {
            float4 v = *(const float4*)(x + (size_t)(rb + rt * 16 + lr) * 128 + kt * 16 + lg4);
            f16x4 h;
            h[0] = (_Float16)v.x; h[1] = (_Float16)v.y;
            h[2] = (_Float16)v.z; h[3] = (_Float16)v.w;
            af[rt][kt] = h;
        }
    const uint2* wb = (const uint2*)(ws + OFF_WP);
    const f32x4 zero4 = {0.f, 0.f, 0.f, 0.f};
    for (int j = 0; j < 10; j++) {
        int nt = w * 10 + j;
        if (nt >= 38) break;
        f16x4 bf[8];
        #pragma unroll
        for (int kt = 0; kt < 8; kt++) {
            uint2 u = wb[(size_t)(nt * 8 + kt) * 64 + lane];
            bf[kt] = *(f16x4*)&u;
        }
        f32x4 acc[4] = {zero4, zero4, zero4, zero4};
        #pragma unroll
        for (int kt = 0; kt < 8; kt++)
            #pragma unroll
            for (int rt = 0; rt < 4; rt++)
                acc[rt] = __builtin_amdgcn_mfma_f32_16x16x16f16(af[rt][kt], bf[kt], acc[rt], 0, 0, 0);
        // scatter: col = nt*16 + lr  ->  d0 = lr; (array,h) from nt alone
        size_t base; int str;
        if (nt < 14) {
            int which = nt >> 1, h = nt & 1;
            base = OFF_T0 + (size_t)which * TSZ + ((size_t)rbq * 24576 + h * 24 + rt_) * 16;
            str = 768;
        } else if (nt < 26) {
            int g = (nt - 14) >> 2, h = (nt - 14) & 3;
            base = OFF_GEOQ + (size_t)g * GSZ + (size_t)(bt * 4 + h) * 8192;
            str = 16;
        } else {
            int np = nt - 26; int isr = np >= 6; int npp = np - (isr ? 6 : 0);
            int g = npp >> 1, h = npp & 1;
            base = (isr ? OFF_RND : OFF_SEM) + (size_t)g * TSZ + (size_t)(bt * 2 + h) * 8192;
            str = 16;
        }
        #pragma unroll
        for (int rt = 0; rt < 4; rt++) {
            int rn0 = rnb + rt * 16;
            #pragma unroll
            for (int i = 0; i < 4; i++)
                ws[base + (size_t)(rn0 + i) * str + lr] = acc[rt][i];
        }
    }
}

// ---------------------------------------------------------------------------
// Generic tiled GEMM: C[M][N] = A[M][K] @ W[K][N] (+bias). BM=BN=64, KT=32.
// ---------------------------------------------------------------------------
__global__ __launch_bounds__(256, 4) void gemm_tile(const float* __restrict__ A,
                                                    const float* __restrict__ W,
                                                    const float* __restrict__ bias,
                                                    float* __restrict__ C,
                                                    int K, int N) {
    __shared__ float a_t[32][68];
    __shared__ float bs[32][64];
    int rb = blockIdx.x * 64, cb = blockIdx.y * 64;
    int t = threadIdx.x, tr = t & 15, tc = t >> 4;
    float acc[4][4] = {{0.f}};
    for (int k0 = 0; k0 < K; k0 += 32) {
        __syncthreads();
        for (int f = t; f < 512; f += 256) {
            int r = f >> 3, kc = f & 7;
            float4 v = *(const float4*)(A + (size_t)(rb + r) * K + k0 + kc * 4);
            a_t[kc * 4 + 0][r] = v.x; a_t[kc * 4 + 1][r] = v.y;
            a_t[kc * 4 + 2][r] = v.z; a_t[kc * 4 + 3][r] = v.w;
        }
        for (int f = t; f < 512; f += 256) {
            int kk = f >> 4, cc = f & 15;
            *(float4*)&bs[kk][cc * 4] = *(const float4*)(W + (size_t)(k0 + kk) * N + cb + cc * 4);
        }
        __syncthreads();
        #pragma unroll
        for (int kk = 0; kk < 32; kk++) {
            float4 a4 = *(const float4*)&a_t[kk][tr * 4];
            float4 b4 = *(const float4*)&bs[kk][tc * 4];
            float av[4] = {a4.x, a4.y, a4.z, a4.w};
            float bv[4] = {b4.x, b4.y, b4.z, b4.w};
            #pragma unroll
            for (int i = 0; i < 4; i++)
                #pragma unroll
                for (int j = 0; j < 4; j++) acc[i][j] += av[i] * bv[j];
        }
    }
    #pragma unroll
    for (int i = 0; i < 4; i++) {
        int row = rb + tr * 4 + i, col = cb + tc * 4;
        float4 o = make_float4(acc[i][0], acc[i][1], acc[i][2], acc[i][3]);
        if (bias) {
            o.x += bias[col]; o.y += bias[col + 1];
            o.z += bias[col + 2]; o.w += bias[col + 3];
        }
        *(float4*)(C + (size_t)row * N + col) = o;
    }
}

// ---------------------------------------------------------------------------
// K3: pattern attention -> k_add, IN-PLACE over the PQ buffer (each thread
// reads its full pq row before overwriting it). No RMW of geo_K; the geo
// spatial staging adds k_add. grid (48, 2), 1 row/thread.
// ---------------------------------------------------------------------------
__global__ __launch_bounds__(256) void pattern_kadd(float* __restrict__ ws) {
    __shared__ float pk[16][64];
    __shared__ float pv[16][64];
    int bt = blockIdx.x, t = threadIdx.x;
    {
        int p = t >> 4, cc = t & 15;
        *(float4*)&pk[p][cc * 4] = *(const float4*)(ws + OFF_PK + (size_t)bt * 1024 + p * 64 + cc * 4);
        *(float4*)&pv[p][cc * 4] = *(const float4*)(ws + OFF_PV + (size_t)bt * 1024 + p * 64 + cc * 4);
    }
    __syncthreads();
    int n = blockIdx.y * 256 + t;
    float* pqr = ws + OFF_PQ + ((size_t)bt * 512 + n) * 64;
    float s[16];
    #pragma unroll
    for (int p = 0; p < 16; p++) s[p] = 0.f;
    #pragma unroll
    for (int j = 0; j < 16; j++) {
        float4 q4 = *(const float4*)(pqr + j * 4);
        #pragma unroll
        for (int p = 0; p < 16; p++) {
            float4 k4 = *(const float4*)&pk[p][j * 4];
            s[p] += q4.x * k4.x + q4.y * k4.y + q4.z * k4.z + q4.w * k4.w;
        }
    }
    float mx = -3e38f;
    #pragma unroll
    for (int p = 0; p < 16; p++) { s[p] *= 0.25f; mx = fmaxf(mx, s[p]); }
    float l = 0.f;
    #pragma unroll
    for (int p = 0; p < 16; p++) { s[p] = __expf(s[p] - mx); l += s[p]; }
    float inv = 1.f / l;
    #pragma unroll
    for (int p = 0; p < 16; p++) s[p] *= inv;
    #pragma unroll
    for (int j = 0; j < 16; j++) {
        float ax = 0.f, ay = 0.f, az = 0.f, aw = 0.f;
        #pragma unroll
        for (int p = 0; p < 16; p++) {
            float4 v4 = *(const float4*)&pv[p][j * 4];
            ax += s[p] * v4.x; ay += s[p] * v4.y; az += s[p] * v4.z; aw += s[p] * v4.w;
        }
        *(float4*)(pqr + j * 4) = make_float4(ax, ay, az, aw);
    }
}

// ---------------------------------------------------------------------------
// K4 (MFMA): spatial attention (validated round 8). Geo heads add k_add
// (from the transformed PQ buffer) during K staging.
// ---------------------------------------------------------------------------
__global__ __launch_bounds__(256) void spatial_attn_mfma(float* __restrict__ ws) {
    __shared__ uint2 ldsK[2048];  // slot[ct*64+l] = K[ct*16+(l&15)][(l>>4)*4+0..3] f16
    __shared__ uint2 ldsV[2048];  // slot[ct*64+l] = V[ct*16+(l>>4)*4+0..3][l&15] f16
    int blk = blockIdx.x;
    int inst = blk >> 1, qhalf = blk & 1;
    int hg = inst & 7, bt = inst >> 3;
    size_t qoff, koff, voff;
    const uint32_t* mbase = (const uint32_t*)(ws + OFF_MB);
    const uint32_t* mb;
    int cbase;
    if (hg < 4) {
        size_t hb = ((size_t)bt * 4 + hg) * 8192;
        qoff = OFF_GEOQ + hb; koff = OFF_GEOK + hb; voff = OFF_GEOV + hb;
        mb = mbase; cbase = 32 + hg * 16;
    } else if (hg < 6) {
        int h = hg - 4; size_t hb = ((size_t)bt * 2 + h) * 8192;
        qoff = OFF_SEM + hb; koff = OFF_SEM + TSZ + hb; voff = OFF_SEM + 2 * TSZ + hb;
        mb = mbase + 8192; cbase = 96 + h * 16;
    } else {
        int h = hg - 6; size_t hb = ((size_t)bt * 2 + h) * 8192;
        qoff = OFF_RND + hb; koff = OFF_RND + TSZ + hb; voff = OFF_RND + 2 * TSZ + hb;
        mb = mbase + 16384; cbase = 128 + h * 16;
    }
    int t = threadIdx.x;
    // --- stage K (A-frag layout), geo adds k_add ---
    {
        const float* Kg = ws + koff;
        const float* KA = ws + OFF_PQ + ((size_t)bt * 512) * 64 + hg * 16;  // valid iff hg<4
        for (int s = t; s < 2048; s += 256) {
            int l = s & 63;
            int row = ((s >> 6) << 4) + (l & 15), dg = (l >> 4) * 4;
            float4 v = *(const float4*)(Kg + (size_t)row * 16 + dg);
            if (hg < 4) {
                float4 a = *(const float4*)(KA + (size_t)row * 64 + dg);
                v.x += a.x; v.y += a.y; v.z += a.z; v.w += a.w;
            }
            f16x4 h;
            h[0] = (_Float16)v.x; h[1] = (_Float16)v.y;
            h[2] = (_Float16)v.z; h[3] = (_Float16)v.w;
            ldsK[s] = *(uint2*)&h;
        }
    }
    // --- stage V (B-frag layout: k-transposed) ---
    {
        const float* Vg = ws + voff;
        for (int s = t; s < 2048; s += 256) {
            int l = s & 63;
            int dcol = l & 15, rb = ((s >> 6) << 4) + (l >> 4) * 4;
            f16x4 h;
            h[0] = (_Float16)Vg[(size_t)(rb + 0) * 16 + dcol];
            h[1] = (_Float16)Vg[(size_t)(rb + 1) * 16 + dcol];
            h[2] = (_Float16)Vg[(size_t)(rb + 2) * 16 + dcol];
            h[3] = (_Float16)Vg[(size_t)(rb + 3) * 16 + dcol];
            ldsV[s] = *(uint2*)&h;
        }
    }
    __syncthreads();
    int lane = t & 63, wave = t >> 6;
    int lq = lane & 15, lg = lane >> 4;
    const float* Qg = ws + qoff;
    float* cat = ws + OFF_CAT;
    const f32x4 zero4 = {0.f, 0.f, 0.f, 0.f};
    for (int jt = 0; jt < 4; jt++) {
        int qt = qhalf * 16 + wave * 4 + jt;   // global q-tile 0..31
        int q = qt * 16 + lq;                  // this lane's softmax row
        float4 qv = *(const float4*)(Qg + (size_t)q * 16 + lg * 4);
        f16x4 qf;                              // pre-scaled by SCALE=0.25
        qf[0] = (_Float16)(qv.x * 0.25f); qf[1] = (_Float16)(qv.y * 0.25f);
        qf[2] = (_Float16)(qv.z * 0.25f); qf[3] = (_Float16)(qv.w * 0.25f);
        f32x4 O = zero4;
        float m = -3e38f, lsum = 0.f;
        const uint32_t* mrow = mb + (size_t)q * 16;
        for (int ch = 0; ch < 4; ch++) {
            uint4 mw = *(const uint4*)(mrow + ch * 4);
            float p[8][4];
            float cm = -3e38f;
            #pragma unroll
            for (int c8 = 0; c8 < 8; c8++) {
                int ct = ch * 8 + c8;
                uint2 kslot = ldsK[ct * 64 + lane];
                f16x4 kf = *(f16x4*)&kslot;
                f32x4 sres = __builtin_amdgcn_mfma_f32_16x16x16f16(kf, qf, zero4, 0, 0, 0);
                uint32_t w = ((const uint32_t*)&mw)[c8 >> 1];
                uint32_t nib = (w >> (((c8 & 1) << 4) + lg * 4)) & 0xFu;
                #pragma unroll
                for (int i = 0; i < 4; i++) {
                    float sv = ((nib >> i) & 1u) ? -1e30f : sres[i];
                    p[c8][i] = sv;
                    cm = fmaxf(cm, sv);
                }
            }
            cm = fmaxf(cm, __shfl_xor(cm, 16));
            cm = fmaxf(cm, __shfl_xor(cm, 32));
            float nm = fmaxf(m, cm);
            float scale = __expf(m - nm);
            m = nm;
            float psum = 0.f;
            #pragma unroll
            for (int c8 = 0; c8 < 8; c8++)
                #pragma unroll
                for (int i = 0; i < 4; i++) {
                    float pv = __expf(p[c8][i] - m);
                    p[c8][i] = pv; psum += pv;
                }
            lsum = lsum * scale + psum;
            #pragma unroll
            for (int i = 0; i < 4; i++) O[i] *= __shfl(scale, lg * 4 + i);
            #pragma unroll
            for (int c8 = 0; c8 < 8; c8++) {
                int ct = ch * 8 + c8;
                f16x4 pf;
                pf[0] = (_Float16)p[c8][0]; pf[1] = (_Float16)p[c8][1];
                pf[2] = (_Float16)p[c8][2]; pf[3] = (_Float16)p[c8][3];
                uint2 vslot = ldsV[ct * 64 + lane];
                f16x4 vf = *(f16x4*)&vslot;
                O = __builtin_amdgcn_mfma_f32_16x16x16f16(pf, vf, O, 0, 0, 0);
            }
        }
        lsum += __shfl_xor(lsum, 16);
        lsum += __shfl_xor(lsum, 32);
        #pragma unroll
        for (int i = 0; i < 4; i++) {
            float ls = __shfl(lsum, lg * 4 + i);
            int qrow = qt * 16 + lg * 4 + i;
            cat[((size_t)bt * 512 + qrow) * 224 + cbase + lq] = O[i] / ls;
        }
    }
}

// ---------------------------------------------------------------------------
// K5: temporal attention (t-branch -> t_x & rt_x, tube-branch -> tube_x).
// ---------------------------------------------------------------------------
__global__ __launch_bounds__(256, 4) void temporal_attn(float* __restrict__ ws) {
    int tid = blockIdx.x * 256 + threadIdx.x;   // 49152 total
    int tt = tid % 24;
    int h  = (tid / 24) & 1;
    int n  = (tid / 48) & 511;
    int b  = tid / 24576;
    size_t base = (((size_t)b * 512 + n) * 2 + h) * 384;
    const float* TQ  = ws + OFF_T0 + 0 * TSZ + base;
    const float* TK  = ws + OFF_T0 + 1 * TSZ + base;
    const float* TV  = ws + OFF_T0 + 2 * TSZ + base;
    const float* RTV = ws + OFF_T0 + 3 * TSZ + base;
    const float* UQ  = ws + OFF_T0 + 4 * TSZ + base;
    const float* UK  = ws + OFF_T0 + 5 * TSZ + base;
    const float* UV  = ws + OFF_T0 + 6 * TSZ + base;
    float* cat = ws + OFF_CAT + (((size_t)b * 24 + tt) * 512 + n) * 224;

    float q[16], p[24];
    // ---- t branch ----
    #pragma unroll
    for (int j = 0; j < 4; j++) {
        float4 v = *(const float4*)(TQ + tt * 16 + j * 4);
        q[j*4+0] = v.x; q[j*4+1] = v.y; q[j*4+2] = v.z; q[j*4+3] = v.w;
    }
    float mx = -3e38f;
    #pragma unroll
    for (int s = 0; s < 24; s++) {
        float d = 0.f;
        #pragma unroll
        for (int j = 0; j < 4; j++) {
            float4 k4 = *(const float4*)(TK + s * 16 + j * 4);
            d += q[j*4+0]*k4.x + q[j*4+1]*k4.y + q[j*4+2]*k4.z + q[j*4+3]*k4.w;
        }
        d *= 0.25f; p[s] = d; mx = fmaxf(mx, d);
    }
    float l = 0.f;
    #pragma unroll
    for (int s = 0; s < 24; s++) { p[s] = __expf(p[s] - mx); l += p[s]; }
    float inv = 1.f / l;
    float a1[16], a2[16];
    #pragma unroll
    for (int d = 0; d < 16; d++) { a1[d] = 0.f; a2[d] = 0.f; }
    #pragma unroll
    for (int s = 0; s < 24; s++) {
        float w = p[s];
        #pragma unroll
        for (int j = 0; j < 4; j++) {
            float4 v4 = *(const float4*)(TV + s * 16 + j * 4);
            a1[j*4+0] += w*v4.x; a1[j*4+1] += w*v4.y; a1[j*4+2] += w*v4.z; a1[j*4+3] += w*v4.w;
            float4 r4 = *(const float4*)(RTV + s * 16 + j * 4);
            a2[j*4+0] += w*r4.x; a2[j*4+1] += w*r4.y; a2[j*4+2] += w*r4.z; a2[j*4+3] += w*r4.w;
        }
    }
    #pragma unroll
    for (int j = 0; j < 4; j++) {
        *(float4*)(cat + 0 + h * 16 + j * 4)   = make_float4(a1[j*4]*inv, a1[j*4+1]*inv, a1[j*4+2]*inv, a1[j*4+3]*inv);
        *(float4*)(cat + 160 + h * 16 + j * 4) = make_float4(a2[j*4]*inv, a2[j*4+1]*inv, a2[j*4+2]*inv, a2[j*4+3]*inv);
    }
    // ---- tube branch ----
    #pragma unroll
    for (int j = 0; j < 4; j++) {
        float4 v = *(const float4*)(UQ + tt * 16 + j * 4);
        q[j*4+0] = v.x; q[j*4+1] = v.y; q[j*4+2] = v.z; q[j*4+3] = v.w;
    }
    mx = -3e38f;
    #pragma unroll
    for (int s = 0; s < 24; s++) {
        float d = 0.f;
        #pragma unroll
        for (int j = 0; j < 4; j++) {
            float4 k4 = *(const float4*)(UK + s * 16 + j * 4);
            d += q[j*4+0]*k4.x + q[j*4+1]*k4.y + q[j*4+2]*k4.z + q[j*4+3]*k4.w;
        }
        d *= 0.25f; p[s] = d; mx = fmaxf(mx, d);
    }
    l = 0.f;
    #pragma unroll
    for (int s = 0; s < 24; s++) { p[s] = __expf(p[s] - mx); l += p[s]; }
    inv = 1.f / l;
    #pragma unroll
    for (int d = 0; d < 16; d++) a1[d] = 0.f;
    #pragma unroll
    for (int s = 0; s < 24; s++) {
        float w = p[s];
        #pragma unroll
        for (int j = 0; j < 4; j++) {
            float4 v4 = *(const float4*)(UV + s * 16 + j * 4);
            a1[j*4+0] += w*v4.x; a1[j*4+1] += w*v4.y; a1[j*4+2] += w*v4.z; a1[j*4+3] += w*v4.w;
        }
    }
    #pragma unroll
    for (int j = 0; j < 4; j++)
        *(float4*)(cat + 192 + h * 16 + j * 4) = make_float4(a1[j*4]*inv, a1[j*4+1]*inv, a1[j*4+2]*inv, a1[j*4+3]*inv);
}

// ---------------------------------------------------------------------------
extern "C" void kernel_launch(void* const* d_in, const int* in_sizes, int n_in,
                              void* d_out, int out_size, void* d_ws, size_t ws_size,
                              hipStream_t stream) {
    const float* x     = (const float*)d_in[0];
    const float* xp    = (const float*)d_in[1];
    const float* pkeys = (const float*)d_in[2];
    float* ws  = (float*)d_ws;
    float* out = (float*)d_out;

    PackPtrs pp;
    pp.w[0]  = (const float*)d_in[6];   // t_wq
    pp.w[1]  = (const float*)d_in[7];   // t_wk
    pp.w[2]  = (const float*)d_in[8];   // t_wv
    pp.w[3]  = (const float*)d_in[24];  // rt_wv
    pp.w[4]  = (const float*)d_in[25];  // tube_wq
    pp.w[5]  = (const float*)d_in[26];  // tube_wk
    pp.w[6]  = (const float*)d_in[27];  // tube_wv
    pp.w[7]  = (const float*)d_in[9];   // geo_wq
    pp.w[8]  = (const float*)d_in[10];  // geo_wk
    pp.w[9]  = (const float*)d_in[11];  // geo_wv
    pp.w[10] = (const float*)d_in[18];  // sem_wq
    pp.w[11] = (const float*)d_in[19];  // sem_wk
    pp.w[12] = (const float*)d_in[20];  // sem_wv
    pp.w[13] = (const float*)d_in[21];  // rnd_wq
    pp.w[14] = (const float*)d_in[22];  // rnd_wk
    pp.w[15] = (const float*)d_in[23];  // rnd_wv
    pp.msk[0] = d_in[3];
    pp.msk[1] = d_in[4];
    pp.msk[2] = d_in[5];

    pack_kernel<<<dim3(176), dim3(256), 0, stream>>>(pp, ws);
    proj_gemm_mfma<<<dim3(384), dim3(256), 0, stream>>>(x, ws);
    gemm_tile<<<dim3(384, 1), dim3(256), 0, stream>>>(xp, (const float*)d_in[12],
              (const float*)d_in[13], ws + OFF_PQ, 128, 64);
    gemm_tile<<<dim3(12, 1), dim3(256), 0, stream>>>(pkeys, (const float*)d_in[14],
              (const float*)d_in[15], ws + OFF_PK, 128, 64);
    gemm_tile<<<dim3(12, 1), dim3(256), 0, stream>>>(pkeys, (const float*)d_in[16],
              (const float*)d_in[17], ws + OFF_PV, 128, 64);
    pattern_kadd<<<dim3(48, 2), dim3(256), 0, stream>>>(ws);
    spatial_attn_mfma<<<dim3(768), dim3(256), 0, stream>>>(ws);
    temporal_attn<<<dim3(192), dim3(256), 0, stream>>>(ws);
    gemm_tile<<<dim3(384, 2), dim3(256), 0, stream>>>(ws + OFF_CAT, (const float*)d_in[28],
              (const float*)d_in[29], out, 224, 128);
}